// Round 13
// baseline (388.206 us; speedup 1.0000x reference)
//
#include <hip/hip_runtime.h>
#include <math.h>

#define N_NODES 100000
#define N_EDGES 1000000
#define D 64
#define N_CONVS 6
#define CAP 64  // max degree bucket (Poisson(10): P(deg>64) ~ 1e-30/node)
#define NDTOT (N_NODES * D)
#define NPART 8           // = XCD count; N_NODES/NPART = 12500 exact
#define CHUNK 4096        // edges per chunk-block

typedef __bf16 bf16x8 __attribute__((ext_vector_type(8)));
typedef float f32x4 __attribute__((ext_vector_type(4)));
typedef float f32x2 __attribute__((ext_vector_type(2)));

static __device__ __forceinline__ float hi2f(unsigned int d) {
    union { unsigned int i; float f; } c; c.i = d & 0xFFFF0000u; return c.f;
}
static __device__ __forceinline__ float lo2f(unsigned int d) {
    union { unsigned int i; float f; } c; c.i = d << 16; return c.f;
}
static __device__ __forceinline__ unsigned short f2bf(float f) {
    union { float f; unsigned int i; } c; c.f = f;
    unsigned int x = c.i;
    unsigned int r = (x + 0x7fffu + ((x >> 16) & 1u)) >> 16;
    return (unsigned short)r;
}

// ---------------- fp8 e4m3 helpers (HW cvt on gfx950; software fallback) ----------------

#if __has_builtin(__builtin_amdgcn_cvt_pk_f32_fp8) && __has_builtin(__builtin_amdgcn_cvt_pk_fp8_f32)
#define HW_FP8 1
#endif

#ifndef HW_FP8
static __device__ __forceinline__ float dec1(unsigned int b) {
    union { unsigned int i; float f; } c;
    c.i = ((b & 0x80u) << 24) | ((b & 0x7fu) << 20);
    return c.f * 0x1p+120f;
}
static __device__ __forceinline__ unsigned int enc1(float f) {
    union { float f; unsigned int i; } c; c.f = f;
    unsigned int s = (c.i >> 24) & 0x80u;
    float a = fabsf(f);
    a = fminf(a, 448.0f);
    c.f = a * 0x1p-120f;
    unsigned int u = c.i;
    unsigned int bits = (u + 0x7FFFFu + ((u >> 20) & 1u)) >> 20;
    if (bits > 0x7Eu) bits = 0x7Eu;
    return s | bits;
}
#endif

static __device__ __forceinline__ void dec8(unsigned int lo, unsigned int hi, float* f) {
#ifdef HW_FP8
    f32x2 p0 = __builtin_amdgcn_cvt_pk_f32_fp8(lo, false);
    f32x2 p1 = __builtin_amdgcn_cvt_pk_f32_fp8(lo, true);
    f32x2 p2 = __builtin_amdgcn_cvt_pk_f32_fp8(hi, false);
    f32x2 p3 = __builtin_amdgcn_cvt_pk_f32_fp8(hi, true);
    f[0] = p0[0]; f[1] = p0[1]; f[2] = p1[0]; f[3] = p1[1];
    f[4] = p2[0]; f[5] = p2[1]; f[6] = p3[0]; f[7] = p3[1];
#else
#pragma unroll
    for (int i = 0; i < 4; ++i) f[i] = dec1((lo >> (8 * i)) & 0xFFu);
#pragma unroll
    for (int i = 0; i < 4; ++i) f[4 + i] = dec1((hi >> (8 * i)) & 0xFFu);
#endif
}

static __device__ __forceinline__ unsigned int enc4(float a, float b, float c2, float d) {
#ifdef HW_FP8
    int r = 0;
    r = __builtin_amdgcn_cvt_pk_fp8_f32(a, b, r, false);
    r = __builtin_amdgcn_cvt_pk_fp8_f32(c2, d, r, true);
    return (unsigned int)r;
#else
    return enc1(a) | (enc1(b) << 8) | (enc1(c2) << 16) | (enc1(d) << 24);
#endif
}

// ---------------- XCD-partitioned bucket-CSR build ----------------

__global__ void fill_cap_part(const int* __restrict__ src, const int* __restrict__ dst,
                              int E, int* __restrict__ cnt, int* __restrict__ colIdx) {
    const int part = blockIdx.x & (NPART - 1);
    const int base = (blockIdx.x >> 3) * CHUNK;
    const int lo = part * (N_NODES / NPART);
    const int hi = lo + (N_NODES / NPART);
#pragma unroll
    for (int it = 0; it < CHUNK / 256; ++it) {
        int e = base + it * 256 + (int)threadIdx.x;
        if (e < E) {
            int d = dst[e];
            if (d >= lo && d < hi) {
                int slot = atomicAdd(&cnt[d], 1);
                if (slot < CAP) colIdx[(size_t)d * CAP + slot] = src[e];
            }
        }
    }
}

// ---------------- prep: fp32->bf16 converts + weight prepack, one launch ----------------

__global__ void prep_all(const float* __restrict__ x, const float* __restrict__ h,
                         unsigned short* __restrict__ xb, unsigned short* __restrict__ hb,
                         const float* __restrict__ Wq, const float* __restrict__ Wk,
                         const float* __restrict__ Wv, const float* __restrict__ Ws,
                         const float* __restrict__ bq, const float* __restrict__ bk,
                         const float* __restrict__ bv, const float* __restrict__ bs,
                         unsigned short* __restrict__ WT, float* __restrict__ ball,
                         int nCvt) {
    int b = blockIdx.x;
    if (b < nCvt) {
        int i = (b * 256 + threadIdx.x) * 4;
        if (i < NDTOT) {
            float4 fx = *(const float4*)&x[i];
            float4 fh = *(const float4*)&h[i];
            ushort4 ux, uh;
            ux.x = f2bf(fx.x); ux.y = f2bf(fx.y); ux.z = f2bf(fx.z); ux.w = f2bf(fx.w);
            uh.x = f2bf(fh.x); uh.y = f2bf(fh.y); uh.z = f2bf(fh.z); uh.w = f2bf(fh.w);
            *(ushort4*)&xb[i] = ux;
            *(ushort4*)&hb[i] = uh;
        }
    } else {
        int idx = (b - nCvt) * 256 + threadIdx.x;   // conv*16384 + n*64 + k
        if (idx >= N_CONVS * 256 * 64) return;
        int conv = idx >> 14;
        int rem = idx & 16383;
        int n = rem >> 6, kk = rem & 63;
        int mat = n >> 6, c = n & 63;
        const float* W = mat == 0 ? Wq : mat == 1 ? Wk : mat == 2 ? Wv : Ws;
        WT[idx] = f2bf(W[conv * 4096 + kk * 64 + c]);
        if (kk == 0) {
            const float* B = mat == 0 ? bq : mat == 1 ? bk : mat == 2 ? bv : bs;
            ball[conv * 256 + n] = B[conv * 64 + c];
        }
    }
}

// ---------------- pair GEMM body (R10-proven): convA(XA) & convB(XB) ----------------
// 512 threads = 8 waves. wave = conv*4 + mat; mat 0..2 -> q/k/v, mat 3 -> skip.
// q -> qboth[node][128] bf16 (qA|qB); k,v -> kv8[node][256] fp8 (kA|vA|kB|vB).

static __device__ __forceinline__ void gemm_pair_body(
    int base,
    const unsigned short* __restrict__ XA, const unsigned short* __restrict__ XB, int N,
    const unsigned short* __restrict__ WTA, const unsigned short* __restrict__ WTB,
    const float* __restrict__ ballA, const float* __restrict__ ballB,
    unsigned short* __restrict__ qboth, unsigned char* __restrict__ kv8,
    float* __restrict__ sk)
{
    __shared__ __align__(16) unsigned short XLA[64][72];
    __shared__ __align__(16) unsigned short XLB[64][72];
    __shared__ __align__(16) float SKIP[64][68];

    const int tid = threadIdx.x;
    const int lane = tid & 63;
    const int wave = tid >> 6;
    const int conv = wave >> 2;
    const int mat = wave & 3;

    {
        int r = tid >> 3, cc = (tid & 7) * 8;
        uint4 va = {0u,0u,0u,0u}, vb = {0u,0u,0u,0u};
        if (base + r < N) {
            va = *(const uint4*)&XA[(size_t)(base + r) * D + cc];
            vb = *(const uint4*)&XB[(size_t)(base + r) * D + cc];
        }
        *(uint4*)&XLA[r][cc] = va;
        *(uint4*)&XLB[r][cc] = vb;
    }
    __syncthreads();

    const int l15 = lane & 15;
    const int lhi = lane >> 4;
    const int n0 = mat * 64;
    const unsigned short* WT = conv ? WTB : WTA;
    const float* ball = conv ? ballB : ballA;

    bf16x8 Wf[4][2];
#pragma unroll
    for (int ni = 0; ni < 4; ++ni)
#pragma unroll
        for (int ks = 0; ks < 2; ++ks)
            Wf[ni][ks] = *(const bf16x8*)&WT[(size_t)(n0 + ni * 16 + l15) * D + lhi * 8 + ks * 32];

    bf16x8 Xf[4][2];
#pragma unroll
    for (int mi = 0; mi < 4; ++mi)
#pragma unroll
        for (int ks = 0; ks < 2; ++ks)
            Xf[mi][ks] = conv ? *(const bf16x8*)&XLB[mi * 16 + l15][lhi * 8 + ks * 32]
                              : *(const bf16x8*)&XLA[mi * 16 + l15][lhi * 8 + ks * 32];

    f32x4 acc[4][4];
#pragma unroll
    for (int ni = 0; ni < 4; ++ni) {
        const float4 b4 = *(const float4*)&ball[n0 + ni * 16 + lhi * 4];
#pragma unroll
        for (int mi = 0; mi < 4; ++mi) {
            f32x4 t;
            t[0] = b4.x; t[1] = b4.y; t[2] = b4.z; t[3] = b4.w;
            acc[mi][ni] = t;
        }
    }

#pragma unroll
    for (int ks = 0; ks < 2; ++ks)
#pragma unroll
        for (int mi = 0; mi < 4; ++mi)
#pragma unroll
            for (int ni = 0; ni < 4; ++ni)
                acc[mi][ni] = __builtin_amdgcn_mfma_f32_16x16x32_bf16(
                    Wf[ni][ks], Xf[mi][ks], acc[mi][ni], 0, 0, 0);

    if (mat == 0) {
        unsigned short* outb = qboth + conv * 64;
#pragma unroll
        for (int mi = 0; mi < 4; ++mi) {
            int row = base + mi * 16 + l15;
            if (row < N) {
#pragma unroll
                for (int ni = 0; ni < 4; ++ni) {
                    int col = ni * 16 + lhi * 4;
                    ushort4 u;
                    u.x = f2bf(acc[mi][ni][0]); u.y = f2bf(acc[mi][ni][1]);
                    u.z = f2bf(acc[mi][ni][2]); u.w = f2bf(acc[mi][ni][3]);
                    *(ushort4*)&outb[(size_t)row * 128 + col] = u;
                }
            }
        }
    } else if (mat < 3) {
        unsigned char* outb = kv8 + conv * 128 + (mat == 2 ? 64 : 0);
#pragma unroll
        for (int mi = 0; mi < 4; ++mi) {
            int row = base + mi * 16 + l15;
            if (row < N) {
#pragma unroll
                for (int ni = 0; ni < 4; ++ni) {
                    int col = ni * 16 + lhi * 4;
                    unsigned int r = enc4(acc[mi][ni][0], acc[mi][ni][1],
                                          acc[mi][ni][2], acc[mi][ni][3]);
                    *(unsigned int*)&outb[(size_t)row * 256 + col] = r;
                }
            }
        }
    } else if (conv == 0) {
#pragma unroll
        for (int mi = 0; mi < 4; ++mi)
#pragma unroll
            for (int ni = 0; ni < 4; ++ni)
                *(f32x4*)&SKIP[mi * 16 + l15][ni * 16 + lhi * 4] = acc[mi][ni];
    }
    __syncthreads();
    if (mat == 3 && conv == 1) {
#pragma unroll
        for (int mi = 0; mi < 4; ++mi) {
            int row = base + mi * 16 + l15;
            if (row < N) {
#pragma unroll
                for (int ni = 0; ni < 4; ++ni) {
                    int col = ni * 16 + lhi * 4;
                    const f32x4 s4 = *(const f32x4*)&SKIP[mi * 16 + l15][col];
                    float4 r4;
                    r4.x = acc[mi][ni][0] + s4[0];
                    r4.y = acc[mi][ni][1] + s4[1];
                    r4.z = acc[mi][ni][2] + s4[2];
                    r4.w = acc[mi][ni][3] + s4[3];
                    *(float4*)&sk[(size_t)row * 64 + col] = r4;
                }
            }
        }
    }
}

// batched: blocks [0,NB) -> convs 0,1 ; blocks [NB,2NB) -> convs 2,3 (grid-level concurrency)
__global__ __launch_bounds__(512) void gemm_pair2(
    const unsigned short* __restrict__ XA, const unsigned short* __restrict__ XB, int N,
    const unsigned short* __restrict__ WT, const float* __restrict__ ball,
    unsigned short* __restrict__ qbothA, unsigned short* __restrict__ qbothB,
    unsigned char* __restrict__ kv8a, unsigned char* __restrict__ kv8b,
    float* __restrict__ zskip, float* __restrict__ rskip, int NB)
{
    const int set = ((int)blockIdx.x >= NB) ? 1 : 0;
    const int base = ((int)blockIdx.x - set * NB) * 64;
    gemm_pair_body(base, XA, XB, N,
                   WT + (size_t)(set * 2) * 256 * 64, WT + (size_t)(set * 2 + 1) * 256 * 64,
                   ball + (size_t)(set * 2) * 256, ball + (size_t)(set * 2 + 1) * 256,
                   set ? qbothB : qbothA, set ? kv8b : kv8a,
                   set ? rskip : zskip);
}

__global__ __launch_bounds__(512) void gemm_pair(
    const unsigned short* __restrict__ XA, const unsigned short* __restrict__ XB, int N,
    const unsigned short* __restrict__ WTA, const unsigned short* __restrict__ WTB,
    const float* __restrict__ ballA, const float* __restrict__ ballB,
    unsigned short* __restrict__ qboth, unsigned char* __restrict__ kv8,
    float* __restrict__ sk)
{
    gemm_pair_body((int)blockIdx.x * 64, XA, XB, N, WTA, WTB, ballA, ballB, qboth, kv8, sk);
}

// ---------------- merged Z+R edge pass: 4 convs, one colIdx walk ----------------
// zb = bf16(sigmoid(zskip + aggZ)); rhb = bf16(sigmoid(rskip + aggR) * h).

__global__ __launch_bounds__(256) void edge_attn_zr(
    const int* __restrict__ cnt, const int* __restrict__ colIdx,
    const unsigned short* __restrict__ qA, const unsigned short* __restrict__ qB,
    const unsigned char* __restrict__ kv8a, const unsigned char* __restrict__ kv8b,
    const float* __restrict__ zskip, const float* __restrict__ rskip,
    const float* __restrict__ hfull,
    unsigned short* __restrict__ zb, unsigned short* __restrict__ rhb, int N)
{
    const int tid = threadIdx.x;
    const int node = blockIdx.x * 32 + (tid >> 3);
    if (node >= N) return;
    const int t = tid & 7;

    int deg = cnt[node];
    if (deg > CAP) deg = CAP;

    const float SC = 0.18033688f;  // 0.125 * log2(e)
    float q[4][8];
    {
        const uint4 u0 = *(const uint4*)&qA[(size_t)node * 128 + t * 8];
        const uint4 u1 = *(const uint4*)&qA[(size_t)node * 128 + 64 + t * 8];
        const uint4 u2 = *(const uint4*)&qB[(size_t)node * 128 + t * 8];
        const uint4 u3 = *(const uint4*)&qB[(size_t)node * 128 + 64 + t * 8];
        const uint4 uu[4] = {u0, u1, u2, u3};
#pragma unroll
        for (int c = 0; c < 4; ++c) {
            q[c][0] = lo2f(uu[c].x) * SC; q[c][1] = hi2f(uu[c].x) * SC;
            q[c][2] = lo2f(uu[c].y) * SC; q[c][3] = hi2f(uu[c].y) * SC;
            q[c][4] = lo2f(uu[c].z) * SC; q[c][5] = hi2f(uu[c].z) * SC;
            q[c][6] = lo2f(uu[c].w) * SC; q[c][7] = hi2f(uu[c].w) * SC;
        }
    }

    const size_t rowbase = (size_t)node * CAP;
    float l[4] = {0.0f, 0.0f, 0.0f, 0.0f};
    float a[4][8];
#pragma unroll
    for (int c = 0; c < 4; ++c)
#pragma unroll
        for (int i = 0; i < 8; ++i) a[c][i] = 0.0f;

    for (int j = 0; j < deg; ++j) {
        const int s = colIdx[rowbase + j];
        const unsigned char* p1 = kv8a + (size_t)s * 256 + t * 8;
        const unsigned char* p2 = kv8b + (size_t)s * 256 + t * 8;
        uint2 kk[4], vv[4];
        kk[0] = *(const uint2*)p1;         vv[0] = *(const uint2*)(p1 + 64);
        kk[1] = *(const uint2*)(p1 + 128); vv[1] = *(const uint2*)(p1 + 192);
        kk[2] = *(const uint2*)p2;         vv[2] = *(const uint2*)(p2 + 64);
        kk[3] = *(const uint2*)(p2 + 128); vv[3] = *(const uint2*)(p2 + 192);

        float pd[4];
#pragma unroll
        for (int c = 0; c < 4; ++c) {
            float kf[8];
            dec8(kk[c].x, kk[c].y, kf);
            pd[c] = q[c][0]*kf[0] + q[c][1]*kf[1] + q[c][2]*kf[2] + q[c][3]*kf[3]
                  + q[c][4]*kf[4] + q[c][5]*kf[5] + q[c][6]*kf[6] + q[c][7]*kf[7];
        }
#pragma unroll
        for (int c = 0; c < 4; ++c) pd[c] += __shfl_xor(pd[c], 1);
#pragma unroll
        for (int c = 0; c < 4; ++c) pd[c] += __shfl_xor(pd[c], 2);
#pragma unroll
        for (int c = 0; c < 4; ++c) pd[c] += __shfl_xor(pd[c], 4);

#pragma unroll
        for (int c = 0; c < 4; ++c) {
            const float wgt = exp2f(pd[c]);
            l[c] += wgt;
            float vf[8];
            dec8(vv[c].x, vv[c].y, vf);
#pragma unroll
            for (int i = 0; i < 8; ++i) a[c][i] += wgt * vf[i];
        }
    }

    float inv[4];
#pragma unroll
    for (int c = 0; c < 4; ++c) inv[c] = 1.0f / (l[c] + 1e-16f);

    const size_t off = (size_t)node * 64 + t * 8;
    const float4 zs1 = *(const float4*)&zskip[off];
    const float4 zs2 = *(const float4*)&zskip[off + 4];
    const float4 rs1 = *(const float4*)&rskip[off];
    const float4 rs2 = *(const float4*)&rskip[off + 4];
    const float4 h1 = *(const float4*)&hfull[off];
    const float4 h2 = *(const float4*)&hfull[off + 4];

    float oz[8], orr[8];
#pragma unroll
    for (int i = 0; i < 8; ++i) {
        oz[i] = a[0][i] * inv[0] + a[1][i] * inv[1];
        orr[i] = a[2][i] * inv[2] + a[3][i] * inv[3];
    }

    ushort4 uz1, uz2, ur1, ur2;
    uz1.x = f2bf(1.0f / (1.0f + __expf(-(zs1.x + oz[0]))));
    uz1.y = f2bf(1.0f / (1.0f + __expf(-(zs1.y + oz[1]))));
    uz1.z = f2bf(1.0f / (1.0f + __expf(-(zs1.z + oz[2]))));
    uz1.w = f2bf(1.0f / (1.0f + __expf(-(zs1.w + oz[3]))));
    uz2.x = f2bf(1.0f / (1.0f + __expf(-(zs2.x + oz[4]))));
    uz2.y = f2bf(1.0f / (1.0f + __expf(-(zs2.y + oz[5]))));
    uz2.z = f2bf(1.0f / (1.0f + __expf(-(zs2.z + oz[6]))));
    uz2.w = f2bf(1.0f / (1.0f + __expf(-(zs2.w + oz[7]))));
    ur1.x = f2bf(h1.x / (1.0f + __expf(-(rs1.x + orr[0]))));
    ur1.y = f2bf(h1.y / (1.0f + __expf(-(rs1.y + orr[1]))));
    ur1.z = f2bf(h1.z / (1.0f + __expf(-(rs1.z + orr[2]))));
    ur1.w = f2bf(h1.w / (1.0f + __expf(-(rs1.w + orr[3]))));
    ur2.x = f2bf(h2.x / (1.0f + __expf(-(rs2.x + orr[4]))));
    ur2.y = f2bf(h2.y / (1.0f + __expf(-(rs2.y + orr[5]))));
    ur2.z = f2bf(h2.z / (1.0f + __expf(-(rs2.z + orr[6]))));
    ur2.w = f2bf(h2.w / (1.0f + __expf(-(rs2.w + orr[7]))));
    *(ushort4*)&zb[off] = uz1;
    *(ushort4*)&zb[off + 4] = uz2;
    *(ushort4*)&rhb[off] = ur1;
    *(ushort4*)&rhb[off + 4] = ur2;
}

// ---------------- final edge pass: convs 4,5 + GRU output (z from bf16) ----------------

__global__ __launch_bounds__(256) void edge_attn_c(
    const int* __restrict__ cnt, const int* __restrict__ colIdx,
    const unsigned short* __restrict__ qptr, const unsigned char* __restrict__ kv8,
    const float* __restrict__ skip, const unsigned short* __restrict__ zb,
    const float* __restrict__ hfull, float* __restrict__ out, int N)
{
    const int tid = threadIdx.x;
    const int node = blockIdx.x * 32 + (tid >> 3);
    if (node >= N) return;
    const int t = tid & 7;

    int deg = cnt[node];
    if (deg > CAP) deg = CAP;

    const float SC = 0.18033688f;
    const uint4 qa4 = *(const uint4*)&qptr[(size_t)node * 128 + t * 8];
    const uint4 qb4 = *(const uint4*)&qptr[(size_t)node * 128 + 64 + t * 8];
    float qa[8], qb[8];
    qa[0] = lo2f(qa4.x) * SC; qa[1] = hi2f(qa4.x) * SC;
    qa[2] = lo2f(qa4.y) * SC; qa[3] = hi2f(qa4.y) * SC;
    qa[4] = lo2f(qa4.z) * SC; qa[5] = hi2f(qa4.z) * SC;
    qa[6] = lo2f(qa4.w) * SC; qa[7] = hi2f(qa4.w) * SC;
    qb[0] = lo2f(qb4.x) * SC; qb[1] = hi2f(qb4.x) * SC;
    qb[2] = lo2f(qb4.y) * SC; qb[3] = hi2f(qb4.y) * SC;
    qb[4] = lo2f(qb4.z) * SC; qb[5] = hi2f(qb4.z) * SC;
    qb[6] = lo2f(qb4.w) * SC; qb[7] = hi2f(qb4.w) * SC;

    const size_t rowbase = (size_t)node * CAP;
    float l0 = 0.0f, l1 = 0.0f;
    float a0[8], a1[8];
#pragma unroll
    for (int i = 0; i < 8; ++i) { a0[i] = 0.0f; a1[i] = 0.0f; }

    for (int j = 0; j < deg; j += 2) {
        const bool v2 = (j + 1) < deg;
        const int s1 = colIdx[rowbase + j];
        const int s2 = colIdx[rowbase + (v2 ? j + 1 : j)];
        const unsigned char* p1 = kv8 + (size_t)s1 * 256 + t * 8;
        const unsigned char* p2 = kv8 + (size_t)s2 * 256 + t * 8;
        const uint2 ka1 = *(const uint2*)p1;
        const uint2 va1 = *(const uint2*)(p1 + 64);
        const uint2 kb1 = *(const uint2*)(p1 + 128);
        const uint2 vb1 = *(const uint2*)(p1 + 192);
        const uint2 ka2 = *(const uint2*)p2;
        const uint2 va2 = *(const uint2*)(p2 + 64);
        const uint2 kb2 = *(const uint2*)(p2 + 128);
        const uint2 vb2 = *(const uint2*)(p2 + 192);

        float kf[8];
        dec8(ka1.x, ka1.y, kf);
        float pa1 = qa[0]*kf[0] + qa[1]*kf[1] + qa[2]*kf[2] + qa[3]*kf[3]
                  + qa[4]*kf[4] + qa[5]*kf[5] + qa[6]*kf[6] + qa[7]*kf[7];
        dec8(kb1.x, kb1.y, kf);
        float pb1 = qb[0]*kf[0] + qb[1]*kf[1] + qb[2]*kf[2] + qb[3]*kf[3]
                  + qb[4]*kf[4] + qb[5]*kf[5] + qb[6]*kf[6] + qb[7]*kf[7];
        dec8(ka2.x, ka2.y, kf);
        float pa2 = qa[0]*kf[0] + qa[1]*kf[1] + qa[2]*kf[2] + qa[3]*kf[3]
                  + qa[4]*kf[4] + qa[5]*kf[5] + qa[6]*kf[6] + qa[7]*kf[7];
        dec8(kb2.x, kb2.y, kf);
        float pb2 = qb[0]*kf[0] + qb[1]*kf[1] + qb[2]*kf[2] + qb[3]*kf[3]
                  + qb[4]*kf[4] + qb[5]*kf[5] + qb[6]*kf[6] + qb[7]*kf[7];

        pa1 += __shfl_xor(pa1, 1); pb1 += __shfl_xor(pb1, 1);
        pa2 += __shfl_xor(pa2, 1); pb2 += __shfl_xor(pb2, 1);
        pa1 += __shfl_xor(pa1, 2); pb1 += __shfl_xor(pb1, 2);
        pa2 += __shfl_xor(pa2, 2); pb2 += __shfl_xor(pb2, 2);
        pa1 += __shfl_xor(pa1, 4); pb1 += __shfl_xor(pb1, 4);
        pa2 += __shfl_xor(pa2, 4); pb2 += __shfl_xor(pb2, 4);

        const float w01 = exp2f(pa1);
        const float w11 = exp2f(pb1);
        const float w02 = v2 ? exp2f(pa2) : 0.0f;
        const float w12 = v2 ? exp2f(pb2) : 0.0f;
        l0 += w01 + w02; l1 += w11 + w12;

        float vf1[8], vf2[8];
        dec8(va1.x, va1.y, vf1);
        dec8(va2.x, va2.y, vf2);
#pragma unroll
        for (int i = 0; i < 8; ++i) a0[i] += w01 * vf1[i] + w02 * vf2[i];
        dec8(vb1.x, vb1.y, vf1);
        dec8(vb2.x, vb2.y, vf2);
#pragma unroll
        for (int i = 0; i < 8; ++i) a1[i] += w11 * vf1[i] + w12 * vf2[i];
    }

    const float inv0 = 1.0f / (l0 + 1e-16f);
    const float inv1 = 1.0f / (l1 + 1e-16f);
    const size_t off = (size_t)node * 64 + t * 8;

    const float4 s1 = *(const float4*)&skip[off];
    const float4 s2 = *(const float4*)&skip[off + 4];
    const float4 h1 = *(const float4*)&hfull[off];
    const float4 h2 = *(const float4*)&hfull[off + 4];
    const uint4 zu = *(const uint4*)&zb[off];   // 8 bf16
    float z[8];
    z[0] = lo2f(zu.x); z[1] = hi2f(zu.x);
    z[2] = lo2f(zu.y); z[3] = hi2f(zu.y);
    z[4] = lo2f(zu.z); z[5] = hi2f(zu.z);
    z[6] = lo2f(zu.w); z[7] = hi2f(zu.w);

    float o[8];
#pragma unroll
    for (int i = 0; i < 8; ++i) o[i] = a0[i] * inv0 + a1[i] * inv1;

    float4 r1, r2;
    r1.x = z[0] * h1.x + (1.0f - z[0]) * tanhf(s1.x + o[0]);
    r1.y = z[1] * h1.y + (1.0f - z[1]) * tanhf(s1.y + o[1]);
    r1.z = z[2] * h1.z + (1.0f - z[2]) * tanhf(s1.z + o[2]);
    r1.w = z[3] * h1.w + (1.0f - z[3]) * tanhf(s1.w + o[3]);
    r2.x = z[4] * h2.x + (1.0f - z[4]) * tanhf(s2.x + o[4]);
    r2.y = z[5] * h2.y + (1.0f - z[5]) * tanhf(s2.y + o[5]);
    r2.z = z[6] * h2.z + (1.0f - z[6]) * tanhf(s2.z + o[6]);
    r2.w = z[7] * h2.w + (1.0f - z[7]) * tanhf(s2.w + o[7]);
    *(float4*)&out[off] = r1;
    *(float4*)&out[off + 4] = r2;
}

// ---------------- launch ----------------

extern "C" void kernel_launch(void* const* d_in, const int* in_sizes, int n_in,
                              void* d_out, int out_size, void* d_ws, size_t ws_size,
                              hipStream_t stream) {
    const int N = N_NODES, E = N_EDGES;
    const float* x  = (const float*)d_in[0];
    const float* h  = (const float*)d_in[1];
    const int*  ei  = (const int*)d_in[2];
    const float* Wq = (const float*)d_in[3];
    const float* bq = (const float*)d_in[4];
    const float* Wk = (const float*)d_in[5];
    const float* bk = (const float*)d_in[6];
    const float* Wv = (const float*)d_in[7];
    const float* bv = (const float*)d_in[8];
    const float* Ws = (const float*)d_in[9];
    const float* bs = (const float*)d_in[10];
    float* out = (float*)d_out;

    const int* src = ei;
    const int* dst = ei + E;

    // ---- workspace layout ----
    char* w = (char*)d_ws;
    int* cnt    = (int*)w;                        // N
    int* colIdx = cnt + N;                        // N*CAP
    size_t intWords = (size_t)N + (size_t)N * CAP;
    char* p = w + ((intWords * 4 + 255) & ~(size_t)255);

    const size_t ND = (size_t)N * D;
    float* zskip = (float*)p;            p += ND * 4;
    float* rskip = (float*)p;            p += ND * 4;   // aliased as cskip after pass ZR
    float* ball  = (float*)p;            p += N_CONVS * 256 * 4;
    unsigned short* xb     = (unsigned short*)p; p += ND * 2;
    unsigned short* hb     = (unsigned short*)p; p += ND * 2;
    unsigned short* rhb    = (unsigned short*)p; p += ND * 2;
    unsigned short* zb     = (unsigned short*)p; p += ND * 2;
    unsigned short* qbothA = (unsigned short*)p; p += ND * 2 * 2;  // [N][128] bf16
    unsigned short* qbothB = (unsigned short*)p; p += ND * 2 * 2;  // [N][128] bf16
    unsigned char*  kv8a   = (unsigned char*)p;  p += (size_t)N_NODES * 256;
    unsigned char*  kv8b   = (unsigned char*)p;  p += (size_t)N_NODES * 256;
    unsigned short* WT     = (unsigned short*)p; p += (size_t)N_CONVS * 256 * 64 * 2;
    float* cskip = rskip;   // gemm45 runs after pass ZR consumed rskip

    const int NB_CVT = (int)(ND / 4 / 256);             // 6250 (exact)
    const int NB_PP = (N_CONVS * 256 * 64 + 255) / 256; // 384
    const int NB_GEMM = (N + 63) / 64;                  // 1563
    const int NB_FILL = ((E + CHUNK - 1) / CHUNK) * NPART;  // 245*8 = 1960
    const int NB_ATTN = (N + 31) / 32;                  // 3125

    prep_all<<<NB_CVT + NB_PP, 256, 0, stream>>>(x, h, xb, hb, Wq, Wk, Wv, Ws,
                                                 bq, bk, bv, bs, WT, ball, NB_CVT);
    hipMemsetAsync(cnt, 0, (size_t)N * sizeof(int), stream);
    fill_cap_part<<<NB_FILL, 256, 0, stream>>>(src, dst, E, cnt, colIdx);

#define WTc(i) (WT + (size_t)(i) * 256 * 64)
#define BLc(i) (ball + (size_t)(i) * 256)

    // convs 0..3 in one batched launch (grid halves; no intra-block coupling)
    gemm_pair2<<<2 * NB_GEMM, 512, 0, stream>>>(
        xb, hb, N, WT, ball, qbothA, qbothB, kv8a, kv8b, zskip, rskip, NB_GEMM);

    // merged pass Z+R: zb = sigmoid(zskip+aggZ) bf16 ; rhb = sigmoid(rskip+aggR)*h bf16
    edge_attn_zr<<<NB_ATTN, 256, 0, stream>>>(
        cnt, colIdx, qbothA, qbothB, kv8a, kv8b, zskip, rskip, h, zb, rhb, N);

    // convs 4,5 (inputs xb, rhb) -> reuse qbothA/kv8a; skip sum -> cskip(=rskip)
    gemm_pair<<<NB_GEMM, 512, 0, stream>>>(
        xb, rhb, N, WTc(4), WTc(5), BLc(4), BLc(5), qbothA, kv8a, cskip);

    // pass C: out = z*h + (1-z)*tanh(cskip + agg(conv4, conv5)), z from zb
    edge_attn_c<<<NB_ATTN, 256, 0, stream>>>(
        cnt, colIdx, qbothA, kv8a, cskip, zb, h, out, N);

#undef WTc
#undef BLc
}

// Round 14
// 351.862 us; speedup vs baseline: 1.1033x; 1.1033x over previous
//
#include <hip/hip_runtime.h>
#include <math.h>

#define N_NODES 100000
#define N_EDGES 1000000
#define D 64
#define N_CONVS 6
#define CAP 64  // max degree bucket (Poisson(10): P(deg>64) ~ 1e-30/node)
#define NDTOT (N_NODES * D)
#define NPART 8           // = XCD count; N_NODES/NPART = 12500 exact
#define CHUNK 4096        // edges per chunk-block

typedef __bf16 bf16x8 __attribute__((ext_vector_type(8)));
typedef float f32x4 __attribute__((ext_vector_type(4)));
typedef float f32x2 __attribute__((ext_vector_type(2)));

static __device__ __forceinline__ float hi2f(unsigned int d) {
    union { unsigned int i; float f; } c; c.i = d & 0xFFFF0000u; return c.f;
}
static __device__ __forceinline__ float lo2f(unsigned int d) {
    union { unsigned int i; float f; } c; c.i = d << 16; return c.f;
}
static __device__ __forceinline__ unsigned short f2bf(float f) {
    union { float f; unsigned int i; } c; c.f = f;
    unsigned int x = c.i;
    unsigned int r = (x + 0x7fffu + ((x >> 16) & 1u)) >> 16;
    return (unsigned short)r;
}

// ---------------- fp8 e4m3 helpers (HW cvt on gfx950; software fallback) ----------------

#if __has_builtin(__builtin_amdgcn_cvt_pk_f32_fp8) && __has_builtin(__builtin_amdgcn_cvt_pk_fp8_f32)
#define HW_FP8 1
#endif

#ifndef HW_FP8
static __device__ __forceinline__ float dec1(unsigned int b) {
    union { unsigned int i; float f; } c;
    c.i = ((b & 0x80u) << 24) | ((b & 0x7fu) << 20);
    return c.f * 0x1p+120f;
}
static __device__ __forceinline__ unsigned int enc1(float f) {
    union { float f; unsigned int i; } c; c.f = f;
    unsigned int s = (c.i >> 24) & 0x80u;
    float a = fabsf(f);
    a = fminf(a, 448.0f);
    c.f = a * 0x1p-120f;
    unsigned int u = c.i;
    unsigned int bits = (u + 0x7FFFFu + ((u >> 20) & 1u)) >> 20;
    if (bits > 0x7Eu) bits = 0x7Eu;
    return s | bits;
}
#endif

static __device__ __forceinline__ void dec8(unsigned int lo, unsigned int hi, float* f) {
#ifdef HW_FP8
    f32x2 p0 = __builtin_amdgcn_cvt_pk_f32_fp8(lo, false);
    f32x2 p1 = __builtin_amdgcn_cvt_pk_f32_fp8(lo, true);
    f32x2 p2 = __builtin_amdgcn_cvt_pk_f32_fp8(hi, false);
    f32x2 p3 = __builtin_amdgcn_cvt_pk_f32_fp8(hi, true);
    f[0] = p0[0]; f[1] = p0[1]; f[2] = p1[0]; f[3] = p1[1];
    f[4] = p2[0]; f[5] = p2[1]; f[6] = p3[0]; f[7] = p3[1];
#else
#pragma unroll
    for (int i = 0; i < 4; ++i) f[i] = dec1((lo >> (8 * i)) & 0xFFu);
#pragma unroll
    for (int i = 0; i < 4; ++i) f[4 + i] = dec1((hi >> (8 * i)) & 0xFFu);
#endif
}

static __device__ __forceinline__ unsigned int enc4(float a, float b, float c2, float d) {
#ifdef HW_FP8
    int r = 0;
    r = __builtin_amdgcn_cvt_pk_fp8_f32(a, b, r, false);
    r = __builtin_amdgcn_cvt_pk_fp8_f32(c2, d, r, true);
    return (unsigned int)r;
#else
    return enc1(a) | (enc1(b) << 8) | (enc1(c2) << 16) | (enc1(d) << 24);
#endif
}

// ---------------- XCD-partitioned bucket-CSR build ----------------

__global__ void fill_cap_part(const int* __restrict__ src, const int* __restrict__ dst,
                              int E, int* __restrict__ cnt, int* __restrict__ colIdx) {
    const int part = blockIdx.x & (NPART - 1);
    const int base = (blockIdx.x >> 3) * CHUNK;
    const int lo = part * (N_NODES / NPART);
    const int hi = lo + (N_NODES / NPART);
#pragma unroll
    for (int it = 0; it < CHUNK / 256; ++it) {
        int e = base + it * 256 + (int)threadIdx.x;
        if (e < E) {
            int d = dst[e];
            if (d >= lo && d < hi) {
                int slot = atomicAdd(&cnt[d], 1);
                if (slot < CAP) colIdx[(size_t)d * CAP + slot] = src[e];
            }
        }
    }
}

// ---------------- prep: fp32->bf16 converts + weight prepack, one launch ----------------

__global__ void prep_all(const float* __restrict__ x, const float* __restrict__ h,
                         unsigned short* __restrict__ xb, unsigned short* __restrict__ hb,
                         const float* __restrict__ Wq, const float* __restrict__ Wk,
                         const float* __restrict__ Wv, const float* __restrict__ Ws,
                         const float* __restrict__ bq, const float* __restrict__ bk,
                         const float* __restrict__ bv, const float* __restrict__ bs,
                         unsigned short* __restrict__ WT, float* __restrict__ ball,
                         int nCvt) {
    int b = blockIdx.x;
    if (b < nCvt) {
        int i = (b * 256 + threadIdx.x) * 4;
        if (i < NDTOT) {
            float4 fx = *(const float4*)&x[i];
            float4 fh = *(const float4*)&h[i];
            ushort4 ux, uh;
            ux.x = f2bf(fx.x); ux.y = f2bf(fx.y); ux.z = f2bf(fx.z); ux.w = f2bf(fx.w);
            uh.x = f2bf(fh.x); uh.y = f2bf(fh.y); uh.z = f2bf(fh.z); uh.w = f2bf(fh.w);
            *(ushort4*)&xb[i] = ux;
            *(ushort4*)&hb[i] = uh;
        }
    } else {
        int idx = (b - nCvt) * 256 + threadIdx.x;   // conv*16384 + n*64 + k
        if (idx >= N_CONVS * 256 * 64) return;
        int conv = idx >> 14;
        int rem = idx & 16383;
        int n = rem >> 6, kk = rem & 63;
        int mat = n >> 6, c = n & 63;
        const float* W = mat == 0 ? Wq : mat == 1 ? Wk : mat == 2 ? Wv : Ws;
        WT[idx] = f2bf(W[conv * 4096 + kk * 64 + c]);
        if (kk == 0) {
            const float* B = mat == 0 ? bq : mat == 1 ? bk : mat == 2 ? bv : bs;
            ball[conv * 256 + n] = B[conv * 64 + c];
        }
    }
}

// ---------------- pair GEMM body (R10-proven): convA(XA) & convB(XB) ----------------
// 512 threads = 8 waves. wave = conv*4 + mat; mat 0..2 -> q/k/v, mat 3 -> skip.
// q -> qboth[node][128] bf16 (qA|qB); k,v -> kv8[node][256] fp8 (kA|vA|kB|vB).

static __device__ __forceinline__ void gemm_pair_body(
    int base,
    const unsigned short* __restrict__ XA, const unsigned short* __restrict__ XB, int N,
    const unsigned short* __restrict__ WTA, const unsigned short* __restrict__ WTB,
    const float* __restrict__ ballA, const float* __restrict__ ballB,
    unsigned short* __restrict__ qboth, unsigned char* __restrict__ kv8,
    float* __restrict__ sk)
{
    __shared__ __align__(16) unsigned short XLA[64][72];
    __shared__ __align__(16) unsigned short XLB[64][72];
    __shared__ __align__(16) float SKIP[64][68];

    const int tid = threadIdx.x;
    const int lane = tid & 63;
    const int wave = tid >> 6;
    const int conv = wave >> 2;
    const int mat = wave & 3;

    {
        int r = tid >> 3, cc = (tid & 7) * 8;
        uint4 va = {0u,0u,0u,0u}, vb = {0u,0u,0u,0u};
        if (base + r < N) {
            va = *(const uint4*)&XA[(size_t)(base + r) * D + cc];
            vb = *(const uint4*)&XB[(size_t)(base + r) * D + cc];
        }
        *(uint4*)&XLA[r][cc] = va;
        *(uint4*)&XLB[r][cc] = vb;
    }
    __syncthreads();

    const int l15 = lane & 15;
    const int lhi = lane >> 4;
    const int n0 = mat * 64;
    const unsigned short* WT = conv ? WTB : WTA;
    const float* ball = conv ? ballB : ballA;

    bf16x8 Wf[4][2];
#pragma unroll
    for (int ni = 0; ni < 4; ++ni)
#pragma unroll
        for (int ks = 0; ks < 2; ++ks)
            Wf[ni][ks] = *(const bf16x8*)&WT[(size_t)(n0 + ni * 16 + l15) * D + lhi * 8 + ks * 32];

    bf16x8 Xf[4][2];
#pragma unroll
    for (int mi = 0; mi < 4; ++mi)
#pragma unroll
        for (int ks = 0; ks < 2; ++ks)
            Xf[mi][ks] = conv ? *(const bf16x8*)&XLB[mi * 16 + l15][lhi * 8 + ks * 32]
                              : *(const bf16x8*)&XLA[mi * 16 + l15][lhi * 8 + ks * 32];

    f32x4 acc[4][4];
#pragma unroll
    for (int ni = 0; ni < 4; ++ni) {
        const float4 b4 = *(const float4*)&ball[n0 + ni * 16 + lhi * 4];
#pragma unroll
        for (int mi = 0; mi < 4; ++mi) {
            f32x4 t;
            t[0] = b4.x; t[1] = b4.y; t[2] = b4.z; t[3] = b4.w;
            acc[mi][ni] = t;
        }
    }

#pragma unroll
    for (int ks = 0; ks < 2; ++ks)
#pragma unroll
        for (int mi = 0; mi < 4; ++mi)
#pragma unroll
            for (int ni = 0; ni < 4; ++ni)
                acc[mi][ni] = __builtin_amdgcn_mfma_f32_16x16x32_bf16(
                    Wf[ni][ks], Xf[mi][ks], acc[mi][ni], 0, 0, 0);

    if (mat == 0) {
        unsigned short* outb = qboth + conv * 64;
#pragma unroll
        for (int mi = 0; mi < 4; ++mi) {
            int row = base + mi * 16 + l15;
            if (row < N) {
#pragma unroll
                for (int ni = 0; ni < 4; ++ni) {
                    int col = ni * 16 + lhi * 4;
                    ushort4 u;
                    u.x = f2bf(acc[mi][ni][0]); u.y = f2bf(acc[mi][ni][1]);
                    u.z = f2bf(acc[mi][ni][2]); u.w = f2bf(acc[mi][ni][3]);
                    *(ushort4*)&outb[(size_t)row * 128 + col] = u;
                }
            }
        }
    } else if (mat < 3) {
        unsigned char* outb = kv8 + conv * 128 + (mat == 2 ? 64 : 0);
#pragma unroll
        for (int mi = 0; mi < 4; ++mi) {
            int row = base + mi * 16 + l15;
            if (row < N) {
#pragma unroll
                for (int ni = 0; ni < 4; ++ni) {
                    int col = ni * 16 + lhi * 4;
                    unsigned int r = enc4(acc[mi][ni][0], acc[mi][ni][1],
                                          acc[mi][ni][2], acc[mi][ni][3]);
                    *(unsigned int*)&outb[(size_t)row * 256 + col] = r;
                }
            }
        }
    } else if (conv == 0) {
#pragma unroll
        for (int mi = 0; mi < 4; ++mi)
#pragma unroll
            for (int ni = 0; ni < 4; ++ni)
                *(f32x4*)&SKIP[mi * 16 + l15][ni * 16 + lhi * 4] = acc[mi][ni];
    }
    __syncthreads();
    if (mat == 3 && conv == 1) {
#pragma unroll
        for (int mi = 0; mi < 4; ++mi) {
            int row = base + mi * 16 + l15;
            if (row < N) {
#pragma unroll
                for (int ni = 0; ni < 4; ++ni) {
                    int col = ni * 16 + lhi * 4;
                    const f32x4 s4 = *(const f32x4*)&SKIP[mi * 16 + l15][col];
                    float4 r4;
                    r4.x = acc[mi][ni][0] + s4[0];
                    r4.y = acc[mi][ni][1] + s4[1];
                    r4.z = acc[mi][ni][2] + s4[2];
                    r4.w = acc[mi][ni][3] + s4[3];
                    *(float4*)&sk[(size_t)row * 64 + col] = r4;
                }
            }
        }
    }
}

// batched: blocks [0,NB) -> convs 0,1 ; blocks [NB,2NB) -> convs 2,3 (grid-level concurrency)
__global__ __launch_bounds__(512) void gemm_pair2(
    const unsigned short* __restrict__ XA, const unsigned short* __restrict__ XB, int N,
    const unsigned short* __restrict__ WT, const float* __restrict__ ball,
    unsigned short* __restrict__ qbothA, unsigned short* __restrict__ qbothB,
    unsigned char* __restrict__ kv8a, unsigned char* __restrict__ kv8b,
    float* __restrict__ zskip, float* __restrict__ rskip, int NB)
{
    const int set = ((int)blockIdx.x >= NB) ? 1 : 0;
    const int base = ((int)blockIdx.x - set * NB) * 64;
    gemm_pair_body(base, XA, XB, N,
                   WT + (size_t)(set * 2) * 256 * 64, WT + (size_t)(set * 2 + 1) * 256 * 64,
                   ball + (size_t)(set * 2) * 256, ball + (size_t)(set * 2 + 1) * 256,
                   set ? qbothB : qbothA, set ? kv8b : kv8a,
                   set ? rskip : zskip);
}

__global__ __launch_bounds__(512) void gemm_pair(
    const unsigned short* __restrict__ XA, const unsigned short* __restrict__ XB, int N,
    const unsigned short* __restrict__ WTA, const unsigned short* __restrict__ WTB,
    const float* __restrict__ ballA, const float* __restrict__ ballB,
    unsigned short* __restrict__ qboth, unsigned char* __restrict__ kv8,
    float* __restrict__ sk)
{
    gemm_pair_body((int)blockIdx.x * 64, XA, XB, N, WTA, WTB, ballA, ballB, qboth, kv8, sk);
}

// ---------------- dual-conv edge attention (R12-proven 2-edge-unrolled body) -------------
// MODE 0 [pass Z]: zb  = bf16(sigmoid(skip + agg))            (sigmoid pre-applied)
// MODE 1 [pass R]: rhb = bf16(sigmoid(skip + agg) * h)        (rpre never materialized)
// MODE 2 [pass C]: out = z*h + (1-z)*tanh(skip + agg), z from bf16 zb.

template<int MODE>
__global__ __launch_bounds__(256) void edge_attn_t(
    const int* __restrict__ cnt, const int* __restrict__ colIdx,
    const unsigned short* __restrict__ qptr,
    const unsigned char* __restrict__ kv8,
    const float* __restrict__ skip, const unsigned short* __restrict__ zbin,
    const float* __restrict__ hfull,
    float* __restrict__ outf, unsigned short* __restrict__ outb16, int N)
{
    const int tid = threadIdx.x;
    const int node = blockIdx.x * 32 + (tid >> 3);
    if (node >= N) return;
    const int t = tid & 7;

    int deg = cnt[node];
    if (deg > CAP) deg = CAP;

    const float SC = 0.18033688f;  // 0.125 * log2(e)
    const uint4 qa4 = *(const uint4*)&qptr[(size_t)node * 128 + t * 8];
    const uint4 qb4 = *(const uint4*)&qptr[(size_t)node * 128 + 64 + t * 8];
    float qa[8], qb[8];
    qa[0] = lo2f(qa4.x) * SC; qa[1] = hi2f(qa4.x) * SC;
    qa[2] = lo2f(qa4.y) * SC; qa[3] = hi2f(qa4.y) * SC;
    qa[4] = lo2f(qa4.z) * SC; qa[5] = hi2f(qa4.z) * SC;
    qa[6] = lo2f(qa4.w) * SC; qa[7] = hi2f(qa4.w) * SC;
    qb[0] = lo2f(qb4.x) * SC; qb[1] = hi2f(qb4.x) * SC;
    qb[2] = lo2f(qb4.y) * SC; qb[3] = hi2f(qb4.y) * SC;
    qb[4] = lo2f(qb4.z) * SC; qb[5] = hi2f(qb4.z) * SC;
    qb[6] = lo2f(qb4.w) * SC; qb[7] = hi2f(qb4.w) * SC;

    const size_t rowbase = (size_t)node * CAP;

    float l0 = 0.0f, l1 = 0.0f;
    float a0[8], a1[8];
#pragma unroll
    for (int i = 0; i < 8; ++i) { a0[i] = 0.0f; a1[i] = 0.0f; }

    for (int j = 0; j < deg; j += 2) {
        const bool v2 = (j + 1) < deg;
        const int s1 = colIdx[rowbase + j];
        const int s2 = colIdx[rowbase + (v2 ? j + 1 : j)];
        const unsigned char* p1 = kv8 + (size_t)s1 * 256 + t * 8;
        const unsigned char* p2 = kv8 + (size_t)s2 * 256 + t * 8;
        const uint2 ka1 = *(const uint2*)p1;
        const uint2 va1 = *(const uint2*)(p1 + 64);
        const uint2 kb1 = *(const uint2*)(p1 + 128);
        const uint2 vb1 = *(const uint2*)(p1 + 192);
        const uint2 ka2 = *(const uint2*)p2;
        const uint2 va2 = *(const uint2*)(p2 + 64);
        const uint2 kb2 = *(const uint2*)(p2 + 128);
        const uint2 vb2 = *(const uint2*)(p2 + 192);

        float kf[8];
        dec8(ka1.x, ka1.y, kf);
        float pa1 = qa[0]*kf[0] + qa[1]*kf[1] + qa[2]*kf[2] + qa[3]*kf[3]
                  + qa[4]*kf[4] + qa[5]*kf[5] + qa[6]*kf[6] + qa[7]*kf[7];
        dec8(kb1.x, kb1.y, kf);
        float pb1 = qb[0]*kf[0] + qb[1]*kf[1] + qb[2]*kf[2] + qb[3]*kf[3]
                  + qb[4]*kf[4] + qb[5]*kf[5] + qb[6]*kf[6] + qb[7]*kf[7];
        dec8(ka2.x, ka2.y, kf);
        float pa2 = qa[0]*kf[0] + qa[1]*kf[1] + qa[2]*kf[2] + qa[3]*kf[3]
                  + qa[4]*kf[4] + qa[5]*kf[5] + qa[6]*kf[6] + qa[7]*kf[7];
        dec8(kb2.x, kb2.y, kf);
        float pb2 = qb[0]*kf[0] + qb[1]*kf[1] + qb[2]*kf[2] + qb[3]*kf[3]
                  + qb[4]*kf[4] + qb[5]*kf[5] + qb[6]*kf[6] + qb[7]*kf[7];

        pa1 += __shfl_xor(pa1, 1); pb1 += __shfl_xor(pb1, 1);
        pa2 += __shfl_xor(pa2, 1); pb2 += __shfl_xor(pb2, 1);
        pa1 += __shfl_xor(pa1, 2); pb1 += __shfl_xor(pb1, 2);
        pa2 += __shfl_xor(pa2, 2); pb2 += __shfl_xor(pb2, 2);
        pa1 += __shfl_xor(pa1, 4); pb1 += __shfl_xor(pb1, 4);
        pa2 += __shfl_xor(pa2, 4); pb2 += __shfl_xor(pb2, 4);

        const float w01 = exp2f(pa1);
        const float w11 = exp2f(pb1);
        const float w02 = v2 ? exp2f(pa2) : 0.0f;
        const float w12 = v2 ? exp2f(pb2) : 0.0f;
        l0 += w01 + w02; l1 += w11 + w12;

        float vf1[8], vf2[8];
        dec8(va1.x, va1.y, vf1);
        dec8(va2.x, va2.y, vf2);
#pragma unroll
        for (int i = 0; i < 8; ++i) a0[i] += w01 * vf1[i] + w02 * vf2[i];
        dec8(vb1.x, vb1.y, vf1);
        dec8(vb2.x, vb2.y, vf2);
#pragma unroll
        for (int i = 0; i < 8; ++i) a1[i] += w11 * vf1[i] + w12 * vf2[i];
    }

    const float inv0 = 1.0f / (l0 + 1e-16f);
    const float inv1 = 1.0f / (l1 + 1e-16f);
    float o[8];
#pragma unroll
    for (int i = 0; i < 8; ++i) o[i] = a0[i] * inv0 + a1[i] * inv1;

    const size_t off = (size_t)node * 64 + t * 8;

    if (MODE == 0) {
        const float4 s1 = *(const float4*)&skip[off];
        const float4 s2 = *(const float4*)&skip[off + 4];
        ushort4 u1, u2;
        u1.x = f2bf(1.0f / (1.0f + __expf(-(s1.x + o[0]))));
        u1.y = f2bf(1.0f / (1.0f + __expf(-(s1.y + o[1]))));
        u1.z = f2bf(1.0f / (1.0f + __expf(-(s1.z + o[2]))));
        u1.w = f2bf(1.0f / (1.0f + __expf(-(s1.w + o[3]))));
        u2.x = f2bf(1.0f / (1.0f + __expf(-(s2.x + o[4]))));
        u2.y = f2bf(1.0f / (1.0f + __expf(-(s2.y + o[5]))));
        u2.z = f2bf(1.0f / (1.0f + __expf(-(s2.z + o[6]))));
        u2.w = f2bf(1.0f / (1.0f + __expf(-(s2.w + o[7]))));
        *(ushort4*)&outb16[off] = u1;
        *(ushort4*)&outb16[off + 4] = u2;
    } else if (MODE == 1) {
        const float4 s1 = *(const float4*)&skip[off];
        const float4 s2 = *(const float4*)&skip[off + 4];
        const float4 h1 = *(const float4*)&hfull[off];
        const float4 h2 = *(const float4*)&hfull[off + 4];
        ushort4 u1, u2;
        u1.x = f2bf(h1.x / (1.0f + __expf(-(s1.x + o[0]))));
        u1.y = f2bf(h1.y / (1.0f + __expf(-(s1.y + o[1]))));
        u1.z = f2bf(h1.z / (1.0f + __expf(-(s1.z + o[2]))));
        u1.w = f2bf(h1.w / (1.0f + __expf(-(s1.w + o[3]))));
        u2.x = f2bf(h2.x / (1.0f + __expf(-(s2.x + o[4]))));
        u2.y = f2bf(h2.y / (1.0f + __expf(-(s2.y + o[5]))));
        u2.z = f2bf(h2.z / (1.0f + __expf(-(s2.z + o[6]))));
        u2.w = f2bf(h2.w / (1.0f + __expf(-(s2.w + o[7]))));
        *(ushort4*)&outb16[off] = u1;
        *(ushort4*)&outb16[off + 4] = u2;
    } else {
        const float4 s1 = *(const float4*)&skip[off];
        const float4 s2 = *(const float4*)&skip[off + 4];
        const float4 h1 = *(const float4*)&hfull[off];
        const float4 h2 = *(const float4*)&hfull[off + 4];
        const uint4 zu = *(const uint4*)&zbin[off];   // 8 bf16 (sigmoid pre-applied)
        float z[8];
        z[0] = lo2f(zu.x); z[1] = hi2f(zu.x);
        z[2] = lo2f(zu.y); z[3] = hi2f(zu.y);
        z[4] = lo2f(zu.z); z[5] = hi2f(zu.z);
        z[6] = lo2f(zu.w); z[7] = hi2f(zu.w);
        float4 r1, r2;
        r1.x = z[0] * h1.x + (1.0f - z[0]) * tanhf(s1.x + o[0]);
        r1.y = z[1] * h1.y + (1.0f - z[1]) * tanhf(s1.y + o[1]);
        r1.z = z[2] * h1.z + (1.0f - z[2]) * tanhf(s1.z + o[2]);
        r1.w = z[3] * h1.w + (1.0f - z[3]) * tanhf(s1.w + o[3]);
        r2.x = z[4] * h2.x + (1.0f - z[4]) * tanhf(s2.x + o[4]);
        r2.y = z[5] * h2.y + (1.0f - z[5]) * tanhf(s2.y + o[5]);
        r2.z = z[6] * h2.z + (1.0f - z[6]) * tanhf(s2.z + o[6]);
        r2.w = z[7] * h2.w + (1.0f - z[7]) * tanhf(s2.w + o[7]);
        *(float4*)&outf[off] = r1;
        *(float4*)&outf[off + 4] = r2;
    }
}

// ---------------- launch ----------------

extern "C" void kernel_launch(void* const* d_in, const int* in_sizes, int n_in,
                              void* d_out, int out_size, void* d_ws, size_t ws_size,
                              hipStream_t stream) {
    const int N = N_NODES, E = N_EDGES;
    const float* x  = (const float*)d_in[0];
    const float* h  = (const float*)d_in[1];
    const int*  ei  = (const int*)d_in[2];
    const float* Wq = (const float*)d_in[3];
    const float* bq = (const float*)d_in[4];
    const float* Wk = (const float*)d_in[5];
    const float* bk = (const float*)d_in[6];
    const float* Wv = (const float*)d_in[7];
    const float* bv = (const float*)d_in[8];
    const float* Ws = (const float*)d_in[9];
    const float* bs = (const float*)d_in[10];
    float* out = (float*)d_out;

    const int* src = ei;
    const int* dst = ei + E;

    // ---- workspace layout ----
    char* w = (char*)d_ws;
    int* cnt    = (int*)w;                        // N
    int* colIdx = cnt + N;                        // N*CAP
    size_t intWords = (size_t)N + (size_t)N * CAP;
    char* p = w + ((intWords * 4 + 255) & ~(size_t)255);

    const size_t ND = (size_t)N * D;
    float* zskip = (float*)p;            p += ND * 4;
    float* rskip = (float*)p;            p += ND * 4;   // aliased as cskip after pass R
    float* ball  = (float*)p;            p += N_CONVS * 256 * 4;
    unsigned short* xb     = (unsigned short*)p; p += ND * 2;
    unsigned short* hb     = (unsigned short*)p; p += ND * 2;
    unsigned short* rhb    = (unsigned short*)p; p += ND * 2;
    unsigned short* zb     = (unsigned short*)p; p += ND * 2;
    unsigned short* qbothA = (unsigned short*)p; p += ND * 2 * 2;  // [N][128] bf16
    unsigned short* qbothB = (unsigned short*)p; p += ND * 2 * 2;  // [N][128] bf16
    unsigned char*  kv8a   = (unsigned char*)p;  p += (size_t)N_NODES * 256;
    unsigned char*  kv8b   = (unsigned char*)p;  p += (size_t)N_NODES * 256;
    unsigned short* WT     = (unsigned short*)p; p += (size_t)N_CONVS * 256 * 64 * 2;
    float* cskip = rskip;   // gemm45 runs after pass R consumed rskip

    const int NB_CVT = (int)(ND / 4 / 256);             // 6250 (exact)
    const int NB_PP = (N_CONVS * 256 * 64 + 255) / 256; // 384
    const int NB_GEMM = (N + 63) / 64;                  // 1563
    const int NB_FILL = ((E + CHUNK - 1) / CHUNK) * NPART;  // 245*8 = 1960
    const int NB_ATTN = (N + 31) / 32;                  // 3125

    prep_all<<<NB_CVT + NB_PP, 256, 0, stream>>>(x, h, xb, hb, Wq, Wk, Wv, Ws,
                                                 bq, bk, bv, bs, WT, ball, NB_CVT);
    hipMemsetAsync(cnt, 0, (size_t)N * sizeof(int), stream);
    fill_cap_part<<<NB_FILL, 256, 0, stream>>>(src, dst, E, cnt, colIdx);

#define WTc(i) (WT + (size_t)(i) * 256 * 64)
#define BLc(i) (ball + (size_t)(i) * 256)

    // convs 0..3 in one batched launch (grid halves; no intra-block coupling)
    gemm_pair2<<<2 * NB_GEMM, 512, 0, stream>>>(
        xb, hb, N, WT, ball, qbothA, qbothB, kv8a, kv8b, zskip, rskip, NB_GEMM);

    // pass Z: zb = bf16(sigmoid(zskip + agg(conv0, conv1)))
    edge_attn_t<0><<<NB_ATTN, 256, 0, stream>>>(
        cnt, colIdx, qbothA, kv8a, zskip, nullptr, nullptr, nullptr, zb, N);

    // pass R: rhb = bf16(sigmoid(rskip + agg(conv2, conv3)) * h)
    edge_attn_t<1><<<NB_ATTN, 256, 0, stream>>>(
        cnt, colIdx, qbothB, kv8b, rskip, nullptr, h, nullptr, rhb, N);

    // convs 4,5 (inputs xb, rhb) -> reuse qbothA/kv8a; skip sum -> cskip(=rskip)
    gemm_pair<<<NB_GEMM, 512, 0, stream>>>(
        xb, rhb, N, WTc(4), WTc(5), BLc(4), BLc(5), qbothA, kv8a, cskip);

    // pass C: out = z*h + (1-z)*tanh(cskip + agg(conv4, conv5)), z from zb
    edge_attn_t<2><<<NB_ATTN, 256, 0, stream>>>(
        cnt, colIdx, qbothA, kv8a, cskip, zb, h, out, nullptr, N);

#undef WTc
#undef BLc
}